// Round 1
// baseline (127.166 us; speedup 1.0000x reference)
//
#include <hip/hip_runtime.h>
#include <hip/hip_bf16.h>

// Problem: B=16, N=1024, M=8192.
//   d[b,n,m] = || binder[b,n,:] - target[m,:] ||
//   attract[b] = mean of 204 smallest (min over m of d[b,n,m]) over n
//   repel[b]   = sum relu(3 - d)^2 over (n,m)
//   out[b] = 10*attract + 5*repel
//
// Kernel 1: pairwise pass. grid (MC=16 m-chunks, NC=4 n-chunks, B=16), 256 thr.
//   LDS-stage 512 targets; each thread owns one binder point (registers),
//   loops chunk; writes min_d2 partial [B][N][MC] and block repel partial.
//   Every ws slot written exactly once -> no init, no atomics, deterministic.
// Kernel 2: per-batch reduce: fold chunk mins, sqrt, bitonic sort 1024,
//   mean of first 204, add repel partials.

#define BB 16
#define NN 1024
#define MM 8192
#define MT 512          // targets per chunk
#define MC (MM / MT)    // 16 m-chunks
#define NT 256          // binder points per block (= threads)
#define NC (NN / NT)    // 4 n-chunks
#define KSEL 204        // int(0.2 * 1024)

__global__ __launch_bounds__(NT) void binder_pair_kernel(
    const float* __restrict__ binder,   // [B, N, 3]
    const float* __restrict__ target,   // [M, 3]
    float* __restrict__ min_part,       // [B, N, MC]
    float* __restrict__ repel_part)     // [B, NC*MC]
{
    __shared__ float t[MT * 3];
    __shared__ float red[NT];

    const int mc  = blockIdx.x;
    const int nc  = blockIdx.y;
    const int b   = blockIdx.z;
    const int tid = threadIdx.x;

    // stage target chunk into LDS (coalesced)
    const float* tbase = target + mc * MT * 3;
    for (int j = tid; j < MT * 3; j += NT) t[j] = tbase[j];
    __syncthreads();

    const int n = nc * NT + tid;
    const float* bp = binder + (b * NN + n) * 3;
    const float x = bp[0], y = bp[1], z = bp[2];

    float mind2 = 3.4e38f;
    float repel = 0.0f;

#pragma unroll 8
    for (int m = 0; m < MT; ++m) {
        // wave-uniform LDS address -> broadcast, conflict-free
        const float dx = x - t[3 * m + 0];
        const float dy = y - t[3 * m + 1];
        const float dz = z - t[3 * m + 2];
        const float d2 = dx * dx + dy * dy + dz * dz;
        mind2 = fminf(mind2, d2);
        if (__builtin_expect(d2 < 9.0f, 0)) {   // rare: keep v_sqrt off hot path
            const float c = 3.0f - sqrtf(d2);
            repel += c * c;
        }
    }

    min_part[(b * NN + n) * MC + mc] = mind2;

    // block-reduce repel
    red[tid] = repel;
    __syncthreads();
    for (int s = NT / 2; s > 0; s >>= 1) {
        if (tid < s) red[tid] += red[tid + s];
        __syncthreads();
    }
    if (tid == 0) repel_part[b * (NC * MC) + nc * MC + mc] = red[0];
}

__global__ __launch_bounds__(1024) void binder_reduce_kernel(
    const float* __restrict__ min_part,    // [B, N, MC]
    const float* __restrict__ repel_part,  // [B, NC*MC]
    float* __restrict__ out)               // [B]
{
    __shared__ float vals[NN];
    __shared__ float red[NN];

    const int b   = blockIdx.x;
    const int tid = threadIdx.x;

    // fold chunk mins, take sqrt
    const float* mp = min_part + (b * NN + tid) * MC;
    float m = 3.4e38f;
#pragma unroll
    for (int c = 0; c < MC; ++c) m = fminf(m, mp[c]);
    vals[tid] = sqrtf(m);
    __syncthreads();

    // bitonic sort ascending, 1024 elements, one element per thread
    for (int k = 2; k <= NN; k <<= 1) {
        for (int j = k >> 1; j > 0; j >>= 1) {
            const int ixj = tid ^ j;
            if (ixj > tid) {
                const float a = vals[tid];
                const float c = vals[ixj];
                const bool asc = ((tid & k) == 0);
                if (asc ? (a > c) : (a < c)) {
                    vals[tid] = c;
                    vals[ixj] = a;
                }
            }
            __syncthreads();
        }
    }

    // sum of the KSEL smallest
    red[tid] = (tid < KSEL) ? vals[tid] : 0.0f;
    __syncthreads();
    for (int s = NN / 2; s > 0; s >>= 1) {
        if (tid < s) red[tid] += red[tid + s];
        __syncthreads();
    }

    if (tid == 0) {
        float repel = 0.0f;
#pragma unroll
        for (int c = 0; c < NC * MC; ++c) repel += repel_part[b * (NC * MC) + c];
        out[b] = 10.0f * (red[0] / (float)KSEL) + 5.0f * repel;
    }
}

extern "C" void kernel_launch(void* const* d_in, const int* in_sizes, int n_in,
                              void* d_out, int out_size, void* d_ws, size_t ws_size,
                              hipStream_t stream) {
    const float* binder = (const float*)d_in[0];   // [16,1024,3] fp32
    const float* target = (const float*)d_in[1];   // [8192,3]   fp32
    float* out = (float*)d_out;                    // [16]       fp32

    float* min_part   = (float*)d_ws;                                  // B*N*MC floats = 1 MiB
    float* repel_part = (float*)((char*)d_ws + (size_t)BB * NN * MC * sizeof(float));

    dim3 g1(MC, NC, BB);   // 16 x 4 x 16 = 1024 blocks
    binder_pair_kernel<<<g1, NT, 0, stream>>>(binder, target, min_part, repel_part);
    binder_reduce_kernel<<<BB, NN, 0, stream>>>(min_part, repel_part, out);
}